// Round 9
// baseline (327.128 us; speedup 1.0000x reference)
//
#include <hip/hip_runtime.h>
#include <hip/hip_bf16.h>

typedef __bf16 bf16x8 __attribute__((ext_vector_type(8)));
typedef float  f32x16 __attribute__((ext_vector_type(16)));
typedef float  f32x4  __attribute__((ext_vector_type(4)));

#define UF_D 256
#define MAP_M 64
#define B_DIM 32
#define U_DIM 512
#define S_DIM 4096

// ---------------------------------------------------------------------------
// Kernel 1 (fused, 512 blocks, two concurrent roles):
//  blocks 0..255   : proj[16384][64] = relu(scale/8 * (ufeat @ v_w^T) + b/8)
//                    - per-block Frobenius norm of v_w (64 KB, L2-hot)
//                    - w fragments: f32 v_w loads + inline bf16 cvt (unscaled;
//                      scale applied once in f32 epilogue — cheaper & exact)
//  blocks 256..511 : mapfeat f32 -> bf16 (32 MB -> 16 MB) so logit reads half
//                    the bytes with zero in-loop converts. NT f32 reads.
// One launch instead of two -> no serialization gap; both roles are BW-bound
// and overlap.
// ---------------------------------------------------------------------------
__global__ __launch_bounds__(256) void fused_prep_proj_kernel(
    const float* __restrict__ ufeat,    // [16384, 256] f32
    const float* __restrict__ v_w,      // [64, 256] f32
    const float* __restrict__ g,        // [1]
    const float* __restrict__ b,        // [64]
    const float* __restrict__ mapfeat,  // [32, 4096, 64] f32
    __bf16* __restrict__ proj,          // [16384, 64] bf16
    __bf16* __restrict__ map_bf16)      // [32, 4096, 64] bf16
{
    const int t = threadIdx.x;

    if (blockIdx.x >= 256) {
        // ---- conversion role ----
        const int cid = blockIdx.x - 256;
        const int NC = (B_DIM * S_DIM * MAP_M) / 8;   // 1,048,576 chunks of 8
        const f32x4* m4 = (const f32x4*)mapfeat;
        bf16x8* o8 = (bf16x8*)map_bf16;
        for (int c = cid * 256 + t; c < NC; c += 256 * 256) {
            f32x4 q0 = __builtin_nontemporal_load(&m4[2 * c]);
            f32x4 q1 = __builtin_nontemporal_load(&m4[2 * c + 1]);
            bf16x8 o;
            o[0] = (__bf16)q0.x; o[1] = (__bf16)q0.y;
            o[2] = (__bf16)q0.z; o[3] = (__bf16)q0.w;
            o[4] = (__bf16)q1.x; o[5] = (__bf16)q1.y;
            o[6] = (__bf16)q1.z; o[7] = (__bf16)q1.w;
            o8[c] = o;
        }
        return;
    }

    // ---- proj role ----
    // Per-block redundant ||V||_F^2 (64 KB, L2-hot after first reader).
    __shared__ float red[256];
    {
        const f32x4* v4 = (const f32x4*)v_w;   // 4096 vec4
        float ss = 0.f;
        for (int i = t; i < 4096; i += 256) {
            f32x4 v = v4[i];
            ss += v.x * v.x + v.y * v.y + v.z * v.z + v.w * v.w;
        }
        red[t] = ss;
        __syncthreads();
        for (int s = 128; s > 0; s >>= 1) {
            if (t < s) red[t] += red[t + s];
            __syncthreads();
        }
    }
    const float s8 = g[0] / (sqrtf(red[0]) * 8.0f);   // scale/8, f32 epilogue

    const int wave = t >> 6;
    const int lane = t & 63;
    const int r  = lane & 31;
    const int kh = lane >> 5;
    const int wr = wave >> 1, wc = wave & 1;
    const int row0 = blockIdx.x * 64 + wr * 32;
    const int col0 = wc * 32;

    f32x16 acc = {};
    const float* ap = ufeat + (size_t)(row0 + r) * UF_D + kh * 8;
    const float* wp = v_w   + (size_t)(col0 + r) * UF_D + kh * 8;

#pragma unroll
    for (int k = 0; k < UF_D; k += 16) {
        f32x4 a01 = *(const f32x4*)(ap + k);
        f32x4 a23 = *(const f32x4*)(ap + k + 4);
        f32x4 w01 = *(const f32x4*)(wp + k);
        f32x4 w23 = *(const f32x4*)(wp + k + 4);
        bf16x8 af, wf;
        af[0] = (__bf16)a01.x; af[1] = (__bf16)a01.y;
        af[2] = (__bf16)a01.z; af[3] = (__bf16)a01.w;
        af[4] = (__bf16)a23.x; af[5] = (__bf16)a23.y;
        af[6] = (__bf16)a23.z; af[7] = (__bf16)a23.w;
        wf[0] = (__bf16)w01.x; wf[1] = (__bf16)w01.y;
        wf[2] = (__bf16)w01.z; wf[3] = (__bf16)w01.w;
        wf[4] = (__bf16)w23.x; wf[5] = (__bf16)w23.y;
        wf[6] = (__bf16)w23.z; wf[7] = (__bf16)w23.w;
        acc = __builtin_amdgcn_mfma_f32_32x32x16_bf16(af, wf, acc, 0, 0, 0);
    }

    // C/D layout: col = lane&31, row = (j&3)+8*(j>>2)+4*(lane>>5)
#pragma unroll
    for (int j = 0; j < 16; ++j) {
        const int rl = (j & 3) + 8 * (j >> 2) + 4 * kh;
        const size_t row = row0 + rl;
        const int col = col0 + r;
        float v = acc[j] * s8 + b[col] * 0.125f;
        proj[row * MAP_M + col] = (__bf16)fmaxf(v, 0.f);
    }
}

// ---------------------------------------------------------------------------
// Kernel 2 (logit): per batch: out[512][4096] = proj_b @ map_b^T, bf16 in.
// 2048 blocks, each does TWO 32u x 512s tiles sharing the same (b,st) map
// slice (map frags L1/L2-hot on the 2nd tile; half the block ramp/tails).
// 4 waves: one 32x128 slice each (1 A-frag + 4 B-frags per k-step).
// Bijective XCD swizzle: each XCD gets 4 consecutive batches; within a batch
// all ut-pairs of an st run consecutively -> 64 KB map slice L2-hot.
// NT stores: full 128-B aligned cachelines, output stream bypasses L2.
// ---------------------------------------------------------------------------
__global__ __launch_bounds__(256) void logit_kernel(
    const __bf16* __restrict__ proj,    // [32, 512, 64] bf16
    const __bf16* __restrict__ map,     // [32, 4096, 64] bf16
    float* __restrict__ out)            // [32, 512, 4096] f32
{
    const int vid = (blockIdx.x & 7) * 256 + (blockIdx.x >> 3);  // XCD swizzle
    const int utp = vid & 7;            // 8 ut-pairs (2 tiles of 32 rows)
    const int st  = (vid >> 3) & 7;     // 8 s-tiles of 512 cols
    const int b   = vid >> 6;           // 32 batches

    const int wave = threadIdx.x >> 6;
    const int lane = threadIdx.x & 63;
    const int r  = lane & 31;
    const int kh = lane >> 5;

    const int s0 = st * 512 + wave * 128;

    const __bf16* A  = proj + (size_t)b * U_DIM * MAP_M;
    const __bf16* Bm = map  + (size_t)b * S_DIM * MAP_M;
    float* O = out + (size_t)b * U_DIM * S_DIM;

    const __bf16* bp0 = Bm + (size_t)(s0 +   0 + r) * MAP_M + kh * 8;
    const __bf16* bp1 = Bm + (size_t)(s0 +  32 + r) * MAP_M + kh * 8;
    const __bf16* bp2 = Bm + (size_t)(s0 +  64 + r) * MAP_M + kh * 8;
    const __bf16* bp3 = Bm + (size_t)(s0 +  96 + r) * MAP_M + kh * 8;

#pragma unroll
    for (int t2 = 0; t2 < 2; ++t2) {
        const int u0 = (utp * 2 + t2) * 32;
        const __bf16* ap = A + (size_t)(u0 + r) * MAP_M + kh * 8;

        f32x16 acc0 = {}, acc1 = {}, acc2 = {}, acc3 = {};

#pragma unroll
        for (int k = 0; k < MAP_M; k += 16) {
            bf16x8 a  = *(const bf16x8*)(ap  + k);
            bf16x8 f0 = *(const bf16x8*)(bp0 + k);
            bf16x8 f1 = *(const bf16x8*)(bp1 + k);
            bf16x8 f2 = *(const bf16x8*)(bp2 + k);
            bf16x8 f3 = *(const bf16x8*)(bp3 + k);
            acc0 = __builtin_amdgcn_mfma_f32_32x32x16_bf16(a, f0, acc0, 0, 0, 0);
            acc1 = __builtin_amdgcn_mfma_f32_32x32x16_bf16(a, f1, acc1, 0, 0, 0);
            acc2 = __builtin_amdgcn_mfma_f32_32x32x16_bf16(a, f2, acc2, 0, 0, 0);
            acc3 = __builtin_amdgcn_mfma_f32_32x32x16_bf16(a, f3, acc3, 0, 0, 0);
        }

#pragma unroll
        for (int j = 0; j < 16; ++j) {
            const int rl = (j & 3) + 8 * (j >> 2) + 4 * kh;
            const size_t row = u0 + rl;
            float* orow = O + row * S_DIM + s0 + r;
            __builtin_nontemporal_store(acc0[j], orow);
            __builtin_nontemporal_store(acc1[j], orow + 32);
            __builtin_nontemporal_store(acc2[j], orow + 64);
            __builtin_nontemporal_store(acc3[j], orow + 96);
        }
    }
}

// ---------------------------------------------------------------------------
extern "C" void kernel_launch(void* const* d_in, const int* in_sizes, int n_in,
                              void* d_out, int out_size, void* d_ws, size_t ws_size,
                              hipStream_t stream) {
    const float* ufeat   = (const float*)d_in[0];   // [32,512,256]
    const float* mapfeat = (const float*)d_in[1];   // [32,4096,64]
    const float* v_w     = (const float*)d_in[2];   // [64,256]
    const float* g       = (const float*)d_in[3];   // [1]
    const float* b       = (const float*)d_in[4];   // [64]
    float* out = (float*)d_out;                     // [32,512,4096]

    __bf16* proj     = (__bf16*)d_ws;                        // 2 MB
    __bf16* map_bf16 = (__bf16*)((char*)d_ws + 2097152);     // 16 MB

    fused_prep_proj_kernel<<<512, 256, 0, stream>>>(ufeat, v_w, g, b, mapfeat,
                                                    proj, map_bf16);
    logit_kernel<<<2048, 256, 0, stream>>>(proj, map_bf16, out);
}